// Round 5
// baseline (89.280 us; speedup 1.0000x reference)
//
#include <hip/hip_runtime.h>

#define NQ 14
#define NSTATE (1 << NQ)

typedef float  f2  __attribute__((ext_vector_type(2)));
typedef __fp16 h2v __attribute__((ext_vector_type(2)));   // matches cvt_pkrtz return type

// ---- LDS layout: state as half2 (4B/amp) so 2 blocks/CU fit (67KB/block) ----
#define OFF_BTAB  (NSTATE*4)
#define OFF_RX3   (OFF_BTAB + 28*8)
#define OFF_XX2   (OFF_RX3 + 28*4)
#define OFF_RED   (OFF_XX2 + 14*4)
#define SMEM_BYTES (OFF_RED + 16*NQ*4)

__device__ __forceinline__ f2 cmul(f2 a, f2 b){
    // (ax*bx - ay*by, ax*by + ay*bx) = ax*b + ay*(-by, bx)  -> pk_mul + pk_fma
    f2 br = {-b.y, b.x};
    return a.x * b + a.y * br;
}

// Apply [[c, -i*sn], [-i*sn, c]] to the (A,B) pair (RX gate / XX coupled pair)
// A' = c*a + sn*(b.y, -b.x);  B' = c*b + sn*(a.y, -a.x)   (packed f32)
__device__ __forceinline__ void rot2(f2& A, f2& B, float c, float sn){
    f2 a = A, b = B;
    f2 ar = {a.y, -a.x};
    f2 br = {b.y, -b.x};
    A = c * a + sn * br;
    B = c * b + sn * ar;
}

__device__ __forceinline__ h2v pack(f2 v){ return __builtin_amdgcn_cvt_pkrtz(v.x, v.y); }
__device__ __forceinline__ f2  unpack(h2v h){ return (f2){(float)h.x, (float)h.y}; }

// bank-conflict swizzle: amplitude i lives at LDS slot sigma(i); involution
__device__ __forceinline__ int slotof(int i){ return i ^ ((i >> 5) & 31); }

// Two XX gates (L bits 3,2 and L bits 1,0) + four RX gates (wires w0..w0+3 on L bits 3..0)
__device__ __forceinline__ void gates16(f2 amp[16], float c0, float s0, float c1, float s1,
                                        const float* rc, const float* rs, int w0)
{
    #pragma unroll
    for (int lo = 0; lo < 4; ++lo) { rot2(amp[lo], amp[lo|12], c0, s0); rot2(amp[lo|4], amp[lo|8], c0, s0); }
    #pragma unroll
    for (int hi = 0; hi < 16; hi += 4) { rot2(amp[hi], amp[hi|3], c1, s1); rot2(amp[hi|1], amp[hi|2], c1, s1); }
    #pragma unroll
    for (int j = 0; j < 4; ++j) {
        const int bm = 1 << (3 - j);
        const float c = rc[w0 + j], s = rs[w0 + j];
        #pragma unroll
        for (int L = 0; L < 16; ++L)
            if (!(L & bm)) rot2(amp[L], amp[L | bm], c, s);
    }
}

// ---- pre-kernel: composed inverse MCX chain -> gather table (SLOT INDEX, incl. swizzle).
// For final index i, source amp j = pi_0(pi_1(...pi_13(i))).
// Transposed layout for per-thread-contiguous loads: tbl[(i&1023)*16 + (i>>10)].
__global__ void perm_tbl_kernel(unsigned short* __restrict__ tbl)
{
    const int i = blockIdx.x * blockDim.x + threadIdx.x;   // 0..16383
    int x = i;
    #pragma unroll
    for (int w = 13; w >= 0; --w) {
        const int p1 = 13 - w;
        const int p2 = 13 - ((w + 1) % NQ);
        const int pt = 13 - ((w + 2) % NQ);
        const int cond = ((x >> p1) & ~(x >> p2)) & 1;
        x ^= cond << pt;
    }
    const int slot = x ^ ((x >> 5) & 31);
    tbl[(i & 1023) * 16 + (i >> 10)] = (unsigned short)slot;
}

__global__ void __launch_bounds__(1024, 8)
qsim_kernel(const float* __restrict__ cp, const float* __restrict__ p,
            const unsigned short* __restrict__ tbl, float* __restrict__ out)
{
    extern __shared__ __align__(16) char smem[];
    h2v* st    = reinterpret_cast<h2v*>(smem);
    f2*  Btab  = reinterpret_cast<f2*>(smem + OFF_BTAB);
    float* rx3c = reinterpret_cast<float*>(smem + OFF_RX3);
    float* rx3s = rx3c + 14;
    float* xx2c = reinterpret_cast<float*>(smem + OFF_XX2);
    float* xx2s = xx2c + 7;
    float* red  = reinterpret_cast<float*>(smem + OFF_RED);

    const int b = blockIdx.x;
    const int t = threadIdx.x;
    const float* pb  = p  + b * 42;   // p[b][3][14]
    const float* cpb = cp + b * 14;   // cp[b][14]

    // ---- per-block tables (RX1 x XX1 x RZ fused into 7 two-qubit blocks) ----
    if (t < 7) {
        const int ws = t, wa = 2*ws, wb = 2*ws + 1;
        float sa, ca; sincosf(0.5f * pb[wa], &sa, &ca);
        float sb, cb; sincosf(0.5f * pb[wb], &sb, &cb);
        f2 s00 = {ca*cb, 0.f};
        f2 s01 = {0.f, -ca*sb};
        f2 s10 = {0.f, -sa*cb};
        f2 s11 = {-sa*sb, 0.f};
        float sx, cx; sincosf(0.5f * cpb[ws], &sx, &cx);
        rot2(s00, s11, cx, sx);
        rot2(s01, s10, cx, sx);
        const float ga = 0.5f * pb[14 + wa], gb = 0.5f * pb[14 + wb];
        float sA, cA; sincosf(ga + gb, &sA, &cA);
        float sB, cB; sincosf(gb - ga, &sB, &cB);
        s00 = cmul(s00, (f2){cA, -sA});
        s11 = cmul(s11, (f2){cA,  sA});
        s01 = cmul(s01, (f2){cB,  sB});
        s10 = cmul(s10, (f2){cB, -sB});
        const int k = 6 - ws;                 // crumb k = index bits (2k+1,2k)
        Btab[k*4+0] = s00; Btab[k*4+1] = s01; Btab[k*4+2] = s10; Btab[k*4+3] = s11;
    } else if (t >= 64 && t < 78) {
        const int w = t - 64;
        float s, c; sincosf(0.5f * pb[28 + w], &s, &c);
        rx3c[w] = c; rx3s[w] = s;
    } else if (t >= 128 && t < 135) {
        const int g = t - 128;
        float s, c; sincosf(0.5f * cpb[7 + g], &s, &c);
        xx2c[g] = c; xx2s[g] = s;
    }
    __syncthreads();

    f2 amp[16];

    // ---- Pass A: build product state + XX(1,2), XX(3,4) + RX3 wires 1..4 (bits 12..9 local)
    {
        const int ibase = (t & 0x1FF) | ((t >> 9) << 13);   // bits 0-8, 13 from thread
        f2 Pc = cmul(cmul(Btab[(ibase & 3)],            Btab[4  + ((ibase >> 2) & 3)]),
                     cmul(Btab[8 + ((ibase >> 4) & 3)], Btab[12 + ((ibase >> 6) & 3)]));
        const int b8  = (ibase >> 8) & 1;
        const int b13 = (ibase >> 13) & 1;
        #pragma unroll
        for (int L = 0; L < 16; ++L) {                       // L bit j -> index bit 9+j
            const int c4 = ((L & 1) << 1) | b8;              // bits (9,8)
            const int c5 = (L >> 1) & 3;                     // bits (11,10)
            const int c6 = (b13 << 1) | ((L >> 3) & 1);      // bits (13,12)
            amp[L] = cmul(cmul(Pc, Btab[16 + c4]), cmul(Btab[20 + c5], Btab[24 + c6]));
        }
        gates16(amp, xx2c[0], xx2s[0], xx2c[1], xx2s[1], rx3c, rx3s, 1);
        #pragma unroll
        for (int L = 0; L < 16; ++L) st[slotof(ibase | (L << 9))] = pack(amp[L]);
    }
    __syncthreads();

    // ---- Pass B: XX(5,6), XX(7,8) + RX3 wires 5..8 (bits 8..5 local)
    {
        const int ibase = (t & 31) | ((t >> 5) << 9);
        #pragma unroll
        for (int L = 0; L < 16; ++L) amp[L] = unpack(st[slotof(ibase | (L << 5))]);
        gates16(amp, xx2c[2], xx2s[2], xx2c[3], xx2s[3], rx3c, rx3s, 5);
        #pragma unroll
        for (int L = 0; L < 16; ++L) st[slotof(ibase | (L << 5))] = pack(amp[L]);
    }
    __syncthreads();

    // ---- Pass C: XX(9,10), XX(11,12) + RX3 wires 9..12 (bits 4..1 local)
    {
        const int ibase = (t & 1) | ((t >> 1) << 5);
        #pragma unroll
        for (int L = 0; L < 16; ++L) amp[L] = unpack(st[slotof(ibase | (L << 1))]);
        gates16(amp, xx2c[4], xx2s[4], xx2c[5], xx2s[5], rx3c, rx3s, 9);
        #pragma unroll
        for (int L = 0; L < 16; ++L) st[slotof(ibase | (L << 1))] = pack(amp[L]);
    }
    __syncthreads();

    // ---- Pass D: XX(13,0) + RX3 wires 13, 0 (bits 0 and 13 local; bits 1,2 filler)
    {
        const int tb = t << 3;   // thread bits -> index bits 3..12
        #pragma unroll
        for (int L = 0; L < 16; ++L) {
            const int i = tb | (L & 1) | (((L >> 1) & 1) << 13) | (((L >> 2) & 1) << 1) | (((L >> 3) & 1) << 2);
            amp[L] = unpack(st[slotof(i)]);
        }
        {   // XX on (wire13 = L bit0, wire0 = L bit1)
            const float c = xx2c[6], s = xx2s[6];
            #pragma unroll
            for (int f = 0; f < 16; f += 4) { rot2(amp[f], amp[f|3], c, s); rot2(amp[f|1], amp[f|2], c, s); }
        }
        {   // RX wire 13 (L bit0)
            const float c = rx3c[13], s = rx3s[13];
            #pragma unroll
            for (int L = 0; L < 16; ++L) if (!(L & 1)) rot2(amp[L], amp[L|1], c, s);
        }
        {   // RX wire 0 (L bit1)
            const float c = rx3c[0], s = rx3s[0];
            #pragma unroll
            for (int L = 0; L < 16; ++L) if (!(L & 2)) rot2(amp[L], amp[L|2], c, s);
        }
        #pragma unroll
        for (int L = 0; L < 16; ++L) {
            const int i = tb | (L & 1) | (((L >> 1) & 1) << 13) | (((L >> 2) & 1) << 1) | (((L >> 3) & 1) << 2);
            st[slotof(i)] = pack(amp[L]);
        }
    }
    __syncthreads();

    // ---- Pass E: table-driven gather over FINAL indices i = t | k<<10.
    // q[i] = |st[tbl[i]]|^2. Wire w <-> i bit (13-w):
    //   wires 0..3  <-> k bits 3..0  (compile-time signs -> T - 2*U)
    //   wires 4..7  <-> wave bits 3..0 (wave-uniform sign of total S)
    //   wires 8..13 <-> lane bits 5..0 (sign-tracking shuffle butterfly)
    {
        unsigned off[16];
        {
            const uint4* tp = reinterpret_cast<const uint4*>(tbl + t * 16);
            const uint4 w0 = tp[0], w1 = tp[1];
            off[0]=w0.x&0xffffu; off[1]=w0.x>>16; off[2]=w0.y&0xffffu; off[3]=w0.y>>16;
            off[4]=w0.z&0xffffu; off[5]=w0.z>>16; off[6]=w0.w&0xffffu; off[7]=w0.w>>16;
            off[8]=w1.x&0xffffu; off[9]=w1.x>>16; off[10]=w1.y&0xffffu; off[11]=w1.y>>16;
            off[12]=w1.z&0xffffu; off[13]=w1.z>>16; off[14]=w1.w&0xffffu; off[15]=w1.w>>16;
        }
        float T = 0.f, U0 = 0.f, U1 = 0.f, U2 = 0.f, U3 = 0.f;
        #pragma unroll
        for (int k = 0; k < 16; ++k) {
            const f2 a = unpack(st[off[k]]);
            const float q = fmaf(a.x, a.x, a.y * a.y);
            T += q;
            if (k & 1) U0 += q;   // i bit10 -> wire 3
            if (k & 2) U1 += q;   // i bit11 -> wire 2
            if (k & 4) U2 += q;   // i bit12 -> wire 1
            if (k & 8) U3 += q;   // i bit13 -> wire 0
        }
        // sign-tracking butterfly over 6 lane bits (valid at lane 0)
        float s = T;
        float d0, d1, d2, d3, d4, d5;
        {
            float o;
            o = __shfl_xor(s, 1);  d0 = s - o; s += o;
            o = __shfl_xor(d0, 2); d0 += o;
            o = __shfl_xor(s, 2);  d1 = s - o; s += o;
            o = __shfl_xor(d0, 4); d0 += o;
            o = __shfl_xor(d1, 4); d1 += o;
            o = __shfl_xor(s, 4);  d2 = s - o; s += o;
            o = __shfl_xor(d0, 8); d0 += o;
            o = __shfl_xor(d1, 8); d1 += o;
            o = __shfl_xor(d2, 8); d2 += o;
            o = __shfl_xor(s, 8);  d3 = s - o; s += o;
            o = __shfl_xor(d0, 16); d0 += o;
            o = __shfl_xor(d1, 16); d1 += o;
            o = __shfl_xor(d2, 16); d2 += o;
            o = __shfl_xor(d3, 16); d3 += o;
            o = __shfl_xor(s, 16);  d4 = s - o; s += o;
            o = __shfl_xor(d0, 32); d0 += o;
            o = __shfl_xor(d1, 32); d1 += o;
            o = __shfl_xor(d2, 32); d2 += o;
            o = __shfl_xor(d3, 32); d3 += o;
            o = __shfl_xor(d4, 32); d4 += o;
            o = __shfl_xor(s, 32);  d5 = s - o; s += o;
        }
        #pragma unroll
        for (int m = 1; m < 64; m <<= 1) {
            U0 += __shfl_xor(U0, m);
            U1 += __shfl_xor(U1, m);
            U2 += __shfl_xor(U2, m);
            U3 += __shfl_xor(U3, m);
        }
        if ((t & 63) == 0) {
            const int v = t >> 6;          // wave index = i bits 9..6
            float* r = red + v * NQ;
            r[0]  = s - 2.f * U3;
            r[1]  = s - 2.f * U2;
            r[2]  = s - 2.f * U1;
            r[3]  = s - 2.f * U0;
            r[4]  = (v & 8) ? -s : s;      // i bit9
            r[5]  = (v & 4) ? -s : s;      // i bit8
            r[6]  = (v & 2) ? -s : s;      // i bit7
            r[7]  = (v & 1) ? -s : s;      // i bit6
            r[8]  = d5;                    // i bit5
            r[9]  = d4;
            r[10] = d3;
            r[11] = d2;
            r[12] = d1;
            r[13] = d0;                    // i bit0 -> wire 13
        }
    }
    __syncthreads();
    if (t < NQ) {
        float ssum = 0.f;
        #pragma unroll
        for (int wv = 0; wv < 16; ++wv) ssum += red[wv * NQ + t];
        out[b * NQ + t] = ssum;
    }
}

extern "C" void kernel_launch(void* const* d_in, const int* in_sizes, int n_in,
                              void* d_out, int out_size, void* d_ws, size_t ws_size,
                              hipStream_t stream)
{
    (void)n_in; (void)out_size; (void)ws_size;
    const float* cp = (const float*)d_in[0];
    const float* p  = (const float*)d_in[1];
    float* out = (float*)d_out;
    unsigned short* tbl = (unsigned short*)d_ws;        // 32 KiB
    const int B = in_sizes[0] / NQ;   // 512

    perm_tbl_kernel<<<NSTATE / 256, 256, 0, stream>>>(tbl);

    (void)hipFuncSetAttribute(reinterpret_cast<const void*>(qsim_kernel),
                              hipFuncAttributeMaxDynamicSharedMemorySize, SMEM_BYTES);
    qsim_kernel<<<B, 1024, SMEM_BYTES, stream>>>(cp, p, tbl, out);
}

// Round 6
// 87.507 us; speedup vs baseline: 1.0203x; 1.0203x over previous
//
#include <hip/hip_runtime.h>

#define NQ 14
#define NSTATE (1 << NQ)

typedef float  f2  __attribute__((ext_vector_type(2)));
typedef __fp16 h2v __attribute__((ext_vector_type(2)));
typedef __fp16 h4v __attribute__((ext_vector_type(4)));

// ---- LDS: gate passes use slotof layout in [0,64K); pass D re-scatters into a
// padded linear layout [0,72K) (18 h2 per thread, stride 72B -> conflict-free b64
// reads in E). The two layouts alias in time (barrier-separated). Tables above 72K.
#define OFF_BTAB  (NSTATE*4 + 1024*8)     // 73728
#define OFF_RX3   (OFF_BTAB + 28*8)
#define OFF_XX2   (OFF_RX3 + 28*4)
#define OFF_RED   (OFF_XX2 + 14*4)
#define SMEM_BYTES (OFF_RED + 16*NQ*4)

__device__ __forceinline__ f2 cmul(f2 a, f2 b){
    f2 br = {-b.y, b.x};
    return a.x * b + a.y * br;
}

// Apply [[c, -i*sn], [-i*sn, c]] to (A,B)
__device__ __forceinline__ void rot2(f2& A, f2& B, float c, float sn){
    f2 a = A, b = B;
    f2 ar = {a.y, -a.x};
    f2 br = {b.y, -b.x};
    A = c * a + sn * br;
    B = c * b + sn * ar;
}

__device__ __forceinline__ h2v pack(f2 v){ return __builtin_amdgcn_cvt_pkrtz(v.x, v.y); }
__device__ __forceinline__ f2  unpack(h2v h){ return (f2){(float)h.x, (float)h.y}; }

// bank swizzle for the gate-pass layout (involution)
__device__ __forceinline__ int slotof(int i){ return i ^ ((i >> 5) & 31); }

// Two XX gates (L bits 3,2 / 1,0) + four RX gates (wires w0..w0+3 on L bits 3..0)
__device__ __forceinline__ void gates16(f2 amp[16], float c0, float s0, float c1, float s1,
                                        const float* rc, const float* rs, int w0)
{
    #pragma unroll
    for (int lo = 0; lo < 4; ++lo) { rot2(amp[lo], amp[lo|12], c0, s0); rot2(amp[lo|4], amp[lo|8], c0, s0); }
    #pragma unroll
    for (int hi = 0; hi < 16; hi += 4) { rot2(amp[hi], amp[hi|3], c1, s1); rot2(amp[hi|1], amp[hi|2], c1, s1); }
    #pragma unroll
    for (int j = 0; j < 4; ++j) {
        const int bm = 1 << (3 - j);
        const float c = rc[w0 + j], s = rs[w0 + j];
        #pragma unroll
        for (int L = 0; L < 16; ++L)
            if (!(L & bm)) rot2(amp[L], amp[L | bm], c, s);
    }
}

// ---- pre-kernel: INVERSE composed perm (ascending w = pi^-1 of the verified
// descending-w gather direction). For pre-perm index j, final position f = pi^-1(j).
// Stored indexed by pass-D's (t,L) enumeration: tblD[t*16+L] = f.
__global__ void perm_tbl_kernel(unsigned short* __restrict__ tblD)
{
    const int j = blockIdx.x * blockDim.x + threadIdx.x;   // 0..16383
    int x = j;
    #pragma unroll
    for (int w = 0; w < NQ; ++w) {          // ascending = inverse chain
        const int p1 = 13 - w;
        const int p2 = 13 - ((w + 1) % NQ);
        const int pt = 13 - ((w + 2) % NQ);
        const int cond = ((x >> p1) & ~(x >> p2)) & 1;
        x ^= cond << pt;
    }
    // D's index pattern: bit0=L0, bit1=L2, bit2=L3, bits3-12=t, bit13=L1
    const int t = (j >> 3) & 0x3FF;
    const int L = (j & 1) | (((j >> 13) & 1) << 1) | (((j >> 1) & 1) << 2) | (((j >> 2) & 1) << 3);
    tblD[t * 16 + L] = (unsigned short)x;
}

__global__ void __launch_bounds__(1024, 8)
qsim_kernel(const float* __restrict__ cp, const float* __restrict__ p,
            const unsigned short* __restrict__ tblD, float* __restrict__ out)
{
    extern __shared__ __align__(16) char smem[];
    h2v* st    = reinterpret_cast<h2v*>(smem);
    f2*  Btab  = reinterpret_cast<f2*>(smem + OFF_BTAB);
    float* rx3c = reinterpret_cast<float*>(smem + OFF_RX3);
    float* rx3s = rx3c + 14;
    float* xx2c = reinterpret_cast<float*>(smem + OFF_XX2);
    float* xx2s = xx2c + 7;
    float* red  = reinterpret_cast<float*>(smem + OFF_RED);

    const int b = blockIdx.x;
    const int t = threadIdx.x;
    const float* pb  = p  + b * 42;   // p[b][3][14]
    const float* cpb = cp + b * 14;   // cp[b][14]

    // ---- per-block tables (RX1 x XX1 x RZ fused into 7 two-qubit blocks) ----
    if (t < 7) {
        const int ws = t, wa = 2*ws, wb = 2*ws + 1;
        float sa, ca; sincosf(0.5f * pb[wa], &sa, &ca);
        float sb, cb; sincosf(0.5f * pb[wb], &sb, &cb);
        f2 s00 = {ca*cb, 0.f};
        f2 s01 = {0.f, -ca*sb};
        f2 s10 = {0.f, -sa*cb};
        f2 s11 = {-sa*sb, 0.f};
        float sx, cx; sincosf(0.5f * cpb[ws], &sx, &cx);
        rot2(s00, s11, cx, sx);
        rot2(s01, s10, cx, sx);
        const float ga = 0.5f * pb[14 + wa], gb = 0.5f * pb[14 + wb];
        float sA, cA; sincosf(ga + gb, &sA, &cA);
        float sB, cB; sincosf(gb - ga, &sB, &cB);
        s00 = cmul(s00, (f2){cA, -sA});
        s11 = cmul(s11, (f2){cA,  sA});
        s01 = cmul(s01, (f2){cB,  sB});
        s10 = cmul(s10, (f2){cB, -sB});
        const int k = 6 - ws;                 // crumb k = index bits (2k+1,2k)
        Btab[k*4+0] = s00; Btab[k*4+1] = s01; Btab[k*4+2] = s10; Btab[k*4+3] = s11;
    } else if (t >= 64 && t < 78) {
        const int w = t - 64;
        float s, c; sincosf(0.5f * pb[28 + w], &s, &c);
        rx3c[w] = c; rx3s[w] = s;
    } else if (t >= 128 && t < 135) {
        const int g = t - 128;
        float s, c; sincosf(0.5f * cpb[7 + g], &s, &c);
        xx2c[g] = c; xx2s[g] = s;
    }
    __syncthreads();

    f2 amp[16];

    // ---- Pass A: product state + XX(1,2), XX(3,4) + RX3 wires 1..4 (bits 12..9 local)
    {
        const int ibase = (t & 0x1FF) | ((t >> 9) << 13);
        f2 Pc = cmul(cmul(Btab[(ibase & 3)],            Btab[4  + ((ibase >> 2) & 3)]),
                     cmul(Btab[8 + ((ibase >> 4) & 3)], Btab[12 + ((ibase >> 6) & 3)]));
        const int b8  = (ibase >> 8) & 1;
        const int b13 = (ibase >> 13) & 1;
        #pragma unroll
        for (int L = 0; L < 16; ++L) {
            const int c4 = ((L & 1) << 1) | b8;
            const int c5 = (L >> 1) & 3;
            const int c6 = (b13 << 1) | ((L >> 3) & 1);
            amp[L] = cmul(cmul(Pc, Btab[16 + c4]), cmul(Btab[20 + c5], Btab[24 + c6]));
        }
        gates16(amp, xx2c[0], xx2s[0], xx2c[1], xx2s[1], rx3c, rx3s, 1);
        #pragma unroll
        for (int L = 0; L < 16; ++L) st[slotof(ibase | (L << 9))] = pack(amp[L]);
    }
    __syncthreads();

    // ---- Pass B: XX(5,6), XX(7,8) + RX3 wires 5..8 (bits 8..5 local)
    {
        const int ibase = (t & 31) | ((t >> 5) << 9);
        #pragma unroll
        for (int L = 0; L < 16; ++L) amp[L] = unpack(st[slotof(ibase | (L << 5))]);
        gates16(amp, xx2c[2], xx2s[2], xx2c[3], xx2s[3], rx3c, rx3s, 5);
        #pragma unroll
        for (int L = 0; L < 16; ++L) st[slotof(ibase | (L << 5))] = pack(amp[L]);
    }
    __syncthreads();

    // ---- Pass C: XX(9,10), XX(11,12) + RX3 wires 9..12 (bits 4..1 local)
    {
        const int ibase = (t & 1) | ((t >> 1) << 5);
        #pragma unroll
        for (int L = 0; L < 16; ++L) amp[L] = unpack(st[slotof(ibase | (L << 1))]);
        gates16(amp, xx2c[4], xx2s[4], xx2c[5], xx2s[5], rx3c, rx3s, 9);
        #pragma unroll
        for (int L = 0; L < 16; ++L) st[slotof(ibase | (L << 1))] = pack(amp[L]);
    }
    __syncthreads();

    // ---- Pass D: XX(13,0) + RX3 wires 13, 0 (bits 0,13 local; bits 1,2 filler),
    // then SCATTER through pi^-1 into the padded linear E-layout (18 h2 / thread).
    {
        // issue the dest-table global loads early (hide latency under LDS reads + gates)
        const uint4* tp = reinterpret_cast<const uint4*>(tblD + t * 16);
        const uint4 w0 = tp[0], w1 = tp[1];

        const int tb = t << 3;
        #pragma unroll
        for (int L = 0; L < 16; ++L) {
            const int i = tb | (L & 1) | (((L >> 1) & 1) << 13) | (((L >> 2) & 1) << 1) | (((L >> 3) & 1) << 2);
            amp[L] = unpack(st[slotof(i)]);
        }
        {   // XX on (wire13 = L bit0, wire0 = L bit1)
            const float c = xx2c[6], s = xx2s[6];
            #pragma unroll
            for (int f = 0; f < 16; f += 4) { rot2(amp[f], amp[f|3], c, s); rot2(amp[f|1], amp[f|2], c, s); }
        }
        {   // RX wire 13 (L bit0)
            const float c = rx3c[13], s = rx3s[13];
            #pragma unroll
            for (int L = 0; L < 16; ++L) if (!(L & 1)) rot2(amp[L], amp[L|1], c, s);
        }
        {   // RX wire 0 (L bit1)
            const float c = rx3c[0], s = rx3s[0];
            #pragma unroll
            for (int L = 0; L < 16; ++L) if (!(L & 2)) rot2(amp[L], amp[L|2], c, s);
        }
        __syncthreads();   // all C-layout reads done; safe to overwrite with E-layout

        unsigned d[16];
        d[0]=w0.x&0xffffu; d[1]=w0.x>>16; d[2]=w0.y&0xffffu; d[3]=w0.y>>16;
        d[4]=w0.z&0xffffu; d[5]=w0.z>>16; d[6]=w0.w&0xffffu; d[7]=w0.w>>16;
        d[8]=w1.x&0xffffu; d[9]=w1.x>>16; d[10]=w1.y&0xffffu; d[11]=w1.y>>16;
        d[12]=w1.z&0xffffu; d[13]=w1.z>>16; d[14]=w1.w&0xffffu; d[15]=w1.w>>16;
        #pragma unroll
        for (int L = 0; L < 16; ++L) {
            const unsigned f = d[L];
            st[f + ((f >> 4) << 1)] = pack(amp[L]);   // h2-idx = (f>>4)*18 + (f&15)
        }
    }
    __syncthreads();

    // ---- Pass E: contiguous conflict-free b64 reads of the final-ordered state.
    // final index i = t*16 + k. Wire w <-> i bit (13-w):
    //   k bits 0..3   -> wires 13..10  (in-loop signed sums U0..U3)
    //   lane bits 0..5 -> wires 9..4   (sign-tracking butterfly d0..d5)
    //   wave bits 0..3 -> wires 3..0   (wave-uniform +-s)
    {
        const h4v* row = reinterpret_cast<const h4v*>(smem + t * 72);
        float T = 0.f, U0 = 0.f, U1 = 0.f, U2 = 0.f, U3 = 0.f;
        #pragma unroll
        for (int m = 0; m < 8; ++m) {          // pair (k=2m, k=2m+1)
            const h4v h = row[m];
            const float a0 = (float)h.x, a1 = (float)h.y;   // amp k=2m
            const float b0 = (float)h.z, b1 = (float)h.w;   // amp k=2m+1
            const float q0 = fmaf(a0, a0, a1 * a1);
            const float q1 = fmaf(b0, b0, b1 * b1);
            const float qs = q0 + q1;
            T += qs;
            U0 += q1;                          // k bit0 set: odd k only
            if (m & 1) U1 += qs;               // k bit1
            if (m & 2) U2 += qs;               // k bit2
            if (m & 4) U3 += qs;               // k bit3
        }
        // sign-tracking butterfly over 6 lane bits (valid at lane 0)
        float s = T;
        float d0, d1, d2, d3, d4, d5;
        {
            float o;
            o = __shfl_xor(s, 1);  d0 = s - o; s += o;
            o = __shfl_xor(d0, 2); d0 += o;
            o = __shfl_xor(s, 2);  d1 = s - o; s += o;
            o = __shfl_xor(d0, 4); d0 += o;
            o = __shfl_xor(d1, 4); d1 += o;
            o = __shfl_xor(s, 4);  d2 = s - o; s += o;
            o = __shfl_xor(d0, 8); d0 += o;
            o = __shfl_xor(d1, 8); d1 += o;
            o = __shfl_xor(d2, 8); d2 += o;
            o = __shfl_xor(s, 8);  d3 = s - o; s += o;
            o = __shfl_xor(d0, 16); d0 += o;
            o = __shfl_xor(d1, 16); d1 += o;
            o = __shfl_xor(d2, 16); d2 += o;
            o = __shfl_xor(d3, 16); d3 += o;
            o = __shfl_xor(s, 16);  d4 = s - o; s += o;
            o = __shfl_xor(d0, 32); d0 += o;
            o = __shfl_xor(d1, 32); d1 += o;
            o = __shfl_xor(d2, 32); d2 += o;
            o = __shfl_xor(d3, 32); d3 += o;
            o = __shfl_xor(d4, 32); d4 += o;
            o = __shfl_xor(s, 32);  d5 = s - o; s += o;
        }
        #pragma unroll
        for (int m = 1; m < 64; m <<= 1) {
            U0 += __shfl_xor(U0, m);
            U1 += __shfl_xor(U1, m);
            U2 += __shfl_xor(U2, m);
            U3 += __shfl_xor(U3, m);
        }
        if ((t & 63) == 0) {
            const int v = t >> 6;              // wave index = i bits 10..13
            float* r = red + v * NQ;
            r[0]  = (v & 8) ? -s : s;          // i bit13 -> wire 0
            r[1]  = (v & 4) ? -s : s;
            r[2]  = (v & 2) ? -s : s;
            r[3]  = (v & 1) ? -s : s;          // i bit10 -> wire 3
            r[4]  = d5;                        // i bit9  -> wire 4
            r[5]  = d4;
            r[6]  = d3;
            r[7]  = d2;
            r[8]  = d1;
            r[9]  = d0;                        // i bit4  -> wire 9
            r[10] = s - 2.f * U3;              // i bit3  -> wire 10
            r[11] = s - 2.f * U2;
            r[12] = s - 2.f * U1;
            r[13] = s - 2.f * U0;              // i bit0  -> wire 13
        }
    }
    __syncthreads();
    if (t < NQ) {
        float ssum = 0.f;
        #pragma unroll
        for (int wv = 0; wv < 16; ++wv) ssum += red[wv * NQ + t];
        out[b * NQ + t] = ssum;
    }
}

extern "C" void kernel_launch(void* const* d_in, const int* in_sizes, int n_in,
                              void* d_out, int out_size, void* d_ws, size_t ws_size,
                              hipStream_t stream)
{
    (void)n_in; (void)out_size; (void)ws_size;
    const float* cp = (const float*)d_in[0];
    const float* p  = (const float*)d_in[1];
    float* out = (float*)d_out;
    unsigned short* tblD = (unsigned short*)d_ws;        // 32 KiB
    const int B = in_sizes[0] / NQ;   // 512

    perm_tbl_kernel<<<NSTATE / 256, 256, 0, stream>>>(tblD);

    (void)hipFuncSetAttribute(reinterpret_cast<const void*>(qsim_kernel),
                              hipFuncAttributeMaxDynamicSharedMemorySize, SMEM_BYTES);
    qsim_kernel<<<B, 1024, SMEM_BYTES, stream>>>(cp, p, tblD, out);
}

// Round 7
// 79.352 us; speedup vs baseline: 1.1251x; 1.1028x over previous
//
#include <hip/hip_runtime.h>

#define NQ 14
#define NSTATE (1 << NQ)
#define NT 256
#define AMPS 64

typedef float  f2  __attribute__((ext_vector_type(2)));
typedef __fp16 h2v __attribute__((ext_vector_type(2)));

// LDS: state h2 (1 dword each). Gate layout slots [0,16384) (XOR-swizzled);
// E layout slots f + (f>>6) in [0,16640) — aliased in time (barrier-separated).
#define N_H2 16640
#define OFF_BTAB  (N_H2*4)
#define OFF_RX3   (OFF_BTAB + 28*8)
#define OFF_XX2   (OFF_RX3 + 28*4)
#define OFF_RED   (OFF_XX2 + 14*4)
#define SMEM_BYTES (OFF_RED + 4*NQ*4)

__device__ __forceinline__ f2 cmul(f2 a, f2 b){
    f2 br = {-b.y, b.x};
    return a.x * b + a.y * br;
}

// t = (ss.lo * y.hi, -ss.hi * y.lo)  -- the (y,-x) swizzle folded into VOP3P
__device__ __forceinline__ f2 pkswz(f2 ss, f2 y){
    f2 t;
    asm("v_pk_mul_f32 %0, %1, %2 op_sel:[0,1] op_sel_hi:[1,0] neg_hi:[0,1]"
        : "=v"(t) : "v"(ss), "v"(y));
    return t;
}
__device__ __forceinline__ f2 pkfma(f2 a, f2 b, f2 c){
    f2 d;
    asm("v_pk_fma_f32 %0, %1, %2, %3" : "=v"(d) : "v"(a), "v"(b), "v"(c));
    return d;
}
// A' = c*A + s*(B.y,-B.x);  B' = c*B + s*(A.y,-A.x)   (4 VOP3P total)
__device__ __forceinline__ void rot2(f2& A, f2& B, f2 cc, f2 ss){
    f2 tA = pkswz(ss, B);
    f2 tB = pkswz(ss, A);
    A = pkfma(cc, A, tA);
    B = pkfma(cc, B, tB);
}

__device__ __forceinline__ h2v pack(f2 v){ return __builtin_amdgcn_cvt_pkrtz(v.x, v.y); }
__device__ __forceinline__ f2  unpack(h2v h){ return (f2){(float)h.x, (float)h.y}; }

template<int P, int M>
__device__ __forceinline__ void applyXX(f2* amp, f2 cc, f2 ss){
    #pragma unroll
    for (int L = 0; L < AMPS; ++L)
        if (!((L >> P) & 1)) rot2(amp[L], amp[L ^ M], cc, ss);
}
template<int R>
__device__ __forceinline__ void applyRX(f2* amp, f2 cc, f2 ss){
    #pragma unroll
    for (int L = 0; L < AMPS; ++L)
        if (!((L >> R) & 1)) rot2(amp[L], amp[L | (1 << R)], cc, ss);
}

// ---- pre-kernel: f = pi^-1(j) (ascending chain; direction verified in R6).
// Stored for P3's (t,L) enumeration, packed 8 consecutive L per thread:
// tblQ[(L>>3)*2048 + t*8 + (L&7)] = f   (u16 units)
__global__ void perm_tbl_kernel(unsigned short* __restrict__ tbl)
{
    const int j = blockIdx.x * blockDim.x + threadIdx.x;   // 0..16383
    int x = j;
    #pragma unroll
    for (int w = 0; w < NQ; ++w) {
        const int p1 = 13 - w;
        const int p2 = 13 - ((w + 1) % NQ);
        const int pt = 13 - ((w + 2) % NQ);
        const int cond = ((x >> p1) & ~(x >> p2)) & 1;
        x ^= cond << pt;
    }
    // P3 mapping: bit1..4 = t0..t3, bit7 = t4, bit5 = t5, bit6 = t6, bit8 = t7;
    //             bit0 = L0, bit13 = L1, bits 9..12 = L2..L5
    const int t = ((j >> 1) & 15) | (((j >> 7) & 1) << 4) | (j & 0x60) | (((j >> 8) & 1) << 7);
    const int L = (j & 1) | (((j >> 13) & 1) << 1) | (((j >> 9) & 15) << 2);
    tbl[(L >> 3) * 2048 + t * 8 + (L & 7)] = (unsigned short)x;
}

__global__ void __launch_bounds__(NT, 2)
qsim_kernel(const float* __restrict__ cp, const float* __restrict__ p,
            const unsigned short* __restrict__ tblD, float* __restrict__ out)
{
    extern __shared__ __align__(16) char smem[];
    h2v* st    = reinterpret_cast<h2v*>(smem);
    f2*  Btab  = reinterpret_cast<f2*>(smem + OFF_BTAB);
    float* rx3c = reinterpret_cast<float*>(smem + OFF_RX3);
    float* rx3s = rx3c + 14;
    float* xx2c = reinterpret_cast<float*>(smem + OFF_XX2);
    float* xx2s = xx2c + 7;
    float* red  = reinterpret_cast<float*>(smem + OFF_RED);

    const int b = blockIdx.x;
    const int t = threadIdx.x;
    const float* pb  = p  + b * 42;   // p[b][3][14]
    const float* cpb = cp + b * 14;   // cp[b][14]

    // ---- per-block tables (RX1 x XX1 x RZ fused into 7 two-qubit blocks) ----
    if (t < 7) {
        const int ws = t, wa = 2*ws, wb = 2*ws + 1;
        float sa, ca; sincosf(0.5f * pb[wa], &sa, &ca);
        float sb, cb; sincosf(0.5f * pb[wb], &sb, &cb);
        f2 s00 = {ca*cb, 0.f};
        f2 s01 = {0.f, -ca*sb};
        f2 s10 = {0.f, -sa*cb};
        f2 s11 = {-sa*sb, 0.f};
        float sx, cx; sincosf(0.5f * cpb[ws], &sx, &cx);
        rot2(s00, s11, (f2){cx,cx}, (f2){sx,sx});
        rot2(s01, s10, (f2){cx,cx}, (f2){sx,sx});
        const float ga = 0.5f * pb[14 + wa], gb = 0.5f * pb[14 + wb];
        float sA, cA; sincosf(ga + gb, &sA, &cA);
        float sB, cB; sincosf(gb - ga, &sB, &cB);
        s00 = cmul(s00, (f2){cA, -sA});
        s11 = cmul(s11, (f2){cA,  sA});
        s01 = cmul(s01, (f2){cB,  sB});
        s10 = cmul(s10, (f2){cB, -sB});
        const int k = 6 - ws;                 // crumb k = state bits (2k+1,2k)
        Btab[k*4+0] = s00; Btab[k*4+1] = s01; Btab[k*4+2] = s10; Btab[k*4+3] = s11;
    } else if (t >= 64 && t < 78) {
        const int w = t - 64;
        float s, c; sincosf(0.5f * pb[28 + w], &s, &c);
        rx3c[w] = c; rx3s[w] = s;
    } else if (t >= 128 && t < 135) {
        const int g = t - 128;
        float s, c; sincosf(0.5f * cpb[7 + g], &s, &c);
        xx2c[g] = c; xx2s[g] = s;
    }
    __syncthreads();

    f2 amp[AMPS];
    f2 cc, ss;
    #define LOADXX(g) do { float c_ = xx2c[g], s_ = xx2s[g]; cc = (f2){c_,c_}; ss = (f2){s_,s_}; } while (0)
    #define LOADRX(w) do { float c_ = rx3c[w], s_ = rx3s[w]; cc = (f2){c_,c_}; ss = (f2){s_,s_}; } while (0)

    // slot(j) = j ^ ((j>>7)&127)   (bank swizzle, involution on low 7 bits)

    // ==== P1: build + XX(1,2),(3,4),(5,6) + RX(1..6).  Local bits {12..7} (L0->bit7).
    // Thread: t[6:0]->bits{6..0}, t7->bit13.
    {
        const int t6 = (t >> 6) & 1, t7 = t >> 7;
        f2 Pc = cmul(cmul(Btab[t & 3], Btab[4 + ((t >> 2) & 3)]), Btab[8 + ((t >> 4) & 3)]);
        f2 P3a0 = cmul(Pc, Btab[12 + t6]);        // L0=0  (c3 idx = L0<<1|t6)
        f2 P3a1 = cmul(Pc, Btab[12 + 2 + t6]);    // L0=1
        f2 G00 = cmul(P3a0, Btab[24 + (t7 << 1)]);      // L5=0 (c6 idx = t7<<1|L5)
        f2 G01 = cmul(P3a0, Btab[24 + (t7 << 1) + 1]);  // L5=1
        f2 G10 = cmul(P3a1, Btab[24 + (t7 << 1)]);
        f2 G11 = cmul(P3a1, Btab[24 + (t7 << 1) + 1]);
        #pragma unroll
        for (int m = 0; m < 16; ++m) {            // m = L[4:1]; c4 = m&3, c5 = m>>2
            f2 H = cmul(Btab[16 + (m & 3)], Btab[20 + (m >> 2)]);
            amp[(m << 1)]          = cmul(G00, H);
            amp[(m << 1) | 1]      = cmul(G10, H);
            amp[32 | (m << 1)]     = cmul(G01, H);
            amp[32 | (m << 1) | 1] = cmul(G11, H);
        }
        LOADXX(0); applyXX<5, 0x30>(amp, cc, ss);   // XX(1,2) on (L5,L4)
        LOADXX(1); applyXX<3, 0x0C>(amp, cc, ss);   // XX(3,4) on (L3,L2)
        LOADXX(2); applyXX<1, 0x03>(amp, cc, ss);   // XX(5,6) on (L1,L0)
        LOADRX(1); applyRX<5>(amp, cc, ss);
        LOADRX(2); applyRX<4>(amp, cc, ss);
        LOADRX(3); applyRX<3>(amp, cc, ss);
        LOADRX(4); applyRX<2>(amp, cc, ss);
        LOADRX(5); applyRX<1>(amp, cc, ss);
        LOADRX(6); applyRX<0>(amp, cc, ss);
        const int jbase = (t7 << 13) | (t & 127);
        #pragma unroll
        for (int L = 0; L < AMPS; ++L) {
            const int j = jbase | (L << 7);
            st[j ^ ((j >> 7) & 127)] = pack(amp[L]);
        }
    }
    __syncthreads();

    // ==== P2: XX(7,8),(9,10),(11,12) + RX(7..12).  Local bits {6..1} (L0->bit1).
    // Thread: t0->bit0, t[7:1]->bits{13..7}.
    {
        const int t0 = t & 1, thi = t >> 1;
        const int hi7 = thi << 7;
        #pragma unroll
        for (int L = 0; L < AMPS; ++L)
            amp[L] = unpack(st[hi7 | (((L << 1) | t0) ^ thi)]);
        LOADXX(3); applyXX<5, 0x30>(amp, cc, ss);   // XX(7,8)  on (L5,L4)
        LOADXX(4); applyXX<3, 0x0C>(amp, cc, ss);   // XX(9,10) on (L3,L2)
        LOADXX(5); applyXX<1, 0x03>(amp, cc, ss);   // XX(11,12) on (L1,L0)
        LOADRX(7);  applyRX<5>(amp, cc, ss);
        LOADRX(8);  applyRX<4>(amp, cc, ss);
        LOADRX(9);  applyRX<3>(amp, cc, ss);
        LOADRX(10); applyRX<2>(amp, cc, ss);
        LOADRX(11); applyRX<1>(amp, cc, ss);
        LOADRX(12); applyRX<0>(amp, cc, ss);
        #pragma unroll
        for (int L = 0; L < AMPS; ++L)
            st[hi7 | (((L << 1) | t0) ^ thi)] = pack(amp[L]);
    }
    __syncthreads();

    // ==== P3: XX(13,0) + RX(13),RX(0), then scatter through pi^-1 to E layout.
    // Local: L0->bit0, L1->bit13, L[5:2]->bits{12..9} (fillers).
    // Thread: t0..t3->bits{1..4}, t4->bit7, t5->bit5, t6->bit6, t7->bit8.
    {
        uint4 tv[8];
        const uint4* tq = reinterpret_cast<const uint4*>(tblD);
        #pragma unroll
        for (int g = 0; g < 8; ++g) tv[g] = tq[g * 256 + t];   // issued early

        const int tbase = ((t & 15) << 1) | (t & 0x60) | (((t >> 4) & 1) << 7) | (((t >> 7) & 1) << 8);
        #pragma unroll
        for (int L = 0; L < AMPS; ++L) {
            const int j = tbase | (L & 1) | (((L >> 1) & 1) << 13) | (((L >> 2) & 15) << 9);
            amp[L] = unpack(st[j ^ ((j >> 7) & 127)]);
        }
        LOADXX(6);  applyXX<0, 0x03>(amp, cc, ss);  // XX(13,0) on (L0,L1)
        LOADRX(13); applyRX<0>(amp, cc, ss);
        LOADRX(0);  applyRX<1>(amp, cc, ss);
        __syncthreads();   // gate-layout reads done; E layout may now overwrite
        #pragma unroll
        for (int L = 0; L < AMPS; ++L) {
            const unsigned comp = (L & 4) ? ((L & 2) ? tv[L >> 3].w : tv[L >> 3].z)
                                          : ((L & 2) ? tv[L >> 3].y : tv[L >> 3].x);
            const unsigned f = (L & 1) ? (comp >> 16) : (comp & 0xffffu);
            st[f + (f >> 6)] = pack(amp[L]);       // eslot = (f>>6)*65 + (f&63)
        }
    }
    __syncthreads();

    // ==== E: contiguous conflict-free reads; final index f = t*64 + k.
    //   k bits 0..5 -> wires 13..8 (in-register tree, U0..U5)
    //   lane bits 0..5 -> wires 7..2 (sign-tracking butterfly d0..d5)
    //   wave bits 0..1 -> wires 1..0 (wave-uniform +-s)
    {
        const h2v* erow = st + t * 65;
        float U0, U1 = 0.f, U2 = 0.f, U4, U5, T;
        float C[8];
        float u0acc = 0.f;
        #pragma unroll
        for (int ch = 0; ch < 8; ++ch) {
            float q[8];
            #pragma unroll
            for (int e = 0; e < 8; ++e) {
                const f2 a = unpack(erow[ch * 8 + e]);
                q[e] = fmaf(a.x, a.x, a.y * a.y);
            }
            const float p0 = q[0] + q[1], p1 = q[2] + q[3], p2 = q[4] + q[5], p3 = q[6] + q[7];
            u0acc += (q[1] + q[3]) + (q[5] + q[7]);
            U1 += p1 + p3;
            const float s01 = p0 + p1, s23 = p2 + p3;
            U2 += s23;
            C[ch] = s01 + s23;
        }
        U0 = u0acc;
        {
            const float P0 = C[0] + C[1], P1 = C[2] + C[3], P2 = C[4] + C[5], P3v = C[6] + C[7];
            const float U3v = (C[1] + C[3]) + (C[5] + C[7]);
            U4 = P1 + P3v;
            const float Q0 = P0 + P1, Q1 = P2 + P3v;
            U5 = Q1;
            T = Q0 + Q1;
            U2 += 0.f; // keep structure
            // stash U3 in C[0] slot to limit live temps
            C[0] = U3v;
        }
        const float U3 = C[0];

        // sign-tracking butterfly over 6 lane bits (results valid at lane 0)
        float s = T;
        float d0, d1, d2, d3, d4, d5;
        {
            float o;
            o = __shfl_xor(s, 1);  d0 = s - o; s += o;
            o = __shfl_xor(d0, 2); d0 += o;
            o = __shfl_xor(s, 2);  d1 = s - o; s += o;
            o = __shfl_xor(d0, 4); d0 += o;
            o = __shfl_xor(d1, 4); d1 += o;
            o = __shfl_xor(s, 4);  d2 = s - o; s += o;
            o = __shfl_xor(d0, 8); d0 += o;
            o = __shfl_xor(d1, 8); d1 += o;
            o = __shfl_xor(d2, 8); d2 += o;
            o = __shfl_xor(s, 8);  d3 = s - o; s += o;
            o = __shfl_xor(d0, 16); d0 += o;
            o = __shfl_xor(d1, 16); d1 += o;
            o = __shfl_xor(d2, 16); d2 += o;
            o = __shfl_xor(d3, 16); d3 += o;
            o = __shfl_xor(s, 16);  d4 = s - o; s += o;
            o = __shfl_xor(d0, 32); d0 += o;
            o = __shfl_xor(d1, 32); d1 += o;
            o = __shfl_xor(d2, 32); d2 += o;
            o = __shfl_xor(d3, 32); d3 += o;
            o = __shfl_xor(d4, 32); d4 += o;
            o = __shfl_xor(s, 32);  d5 = s - o; s += o;
        }
        float V0 = U0, V1 = U1, V2 = U2, V3 = U3, V4 = U4, V5 = U5;
        #pragma unroll
        for (int m = 1; m < 64; m <<= 1) {
            V0 += __shfl_xor(V0, m);
            V1 += __shfl_xor(V1, m);
            V2 += __shfl_xor(V2, m);
            V3 += __shfl_xor(V3, m);
            V4 += __shfl_xor(V4, m);
            V5 += __shfl_xor(V5, m);
        }
        if ((t & 63) == 0) {
            const int wv = t >> 6;           // wave bits = f bits 12,13
            float* r = red + wv * NQ;
            r[0]  = (wv & 2) ? -s : s;       // f bit13 -> wire 0
            r[1]  = (wv & 1) ? -s : s;       // f bit12 -> wire 1
            r[2]  = d5;                      // f bit11 (t5) -> wire 2
            r[3]  = d4;
            r[4]  = d3;
            r[5]  = d2;
            r[6]  = d1;
            r[7]  = d0;                      // f bit6 (t0) -> wire 7
            r[8]  = s - 2.f * V5;            // f bit5 -> wire 8
            r[9]  = s - 2.f * V4;
            r[10] = s - 2.f * V3;
            r[11] = s - 2.f * V2;
            r[12] = s - 2.f * V1;
            r[13] = s - 2.f * V0;            // f bit0 -> wire 13
        }
    }
    __syncthreads();
    if (t < NQ) {
        out[b * NQ + t] = (red[t] + red[NQ + t]) + (red[2 * NQ + t] + red[3 * NQ + t]);
    }
    #undef LOADXX
    #undef LOADRX
}

extern "C" void kernel_launch(void* const* d_in, const int* in_sizes, int n_in,
                              void* d_out, int out_size, void* d_ws, size_t ws_size,
                              hipStream_t stream)
{
    (void)n_in; (void)out_size; (void)ws_size;
    const float* cp = (const float*)d_in[0];
    const float* p  = (const float*)d_in[1];
    float* out = (float*)d_out;
    unsigned short* tbl = (unsigned short*)d_ws;        // 32 KiB
    const int B = in_sizes[0] / NQ;   // 512

    perm_tbl_kernel<<<NSTATE / 256, 256, 0, stream>>>(tbl);

    (void)hipFuncSetAttribute(reinterpret_cast<const void*>(qsim_kernel),
                              hipFuncAttributeMaxDynamicSharedMemorySize, SMEM_BYTES);
    qsim_kernel<<<B, NT, SMEM_BYTES, stream>>>(cp, p, tbl, out);
}